// Round 12
// baseline (386.051 us; speedup 1.0000x reference)
//
#include <hip/hip_runtime.h>
#include <hip/hip_bf16.h>

#define B_    16
#define CI_   512
#define CO_   128
#define QS    64
#define NWAVE 8
#define IPW   (CI_ / NWAVE)   // 64 capsules_in per wave

static constexpr float LAMB = 0.2f;
// exp(-0.5*x) == exp2f(x * NEG_HALF_LOG2E)
static constexpr float NEG_HALF_LOG2E = -0.72134752044448170368f;

// ---------- wave reduction: DPP (VALU pipe) intra-16, swizzle/shfl for 16/32 ----------
template <int CTRL>
__device__ __forceinline__ float dpp_add(float v) {
    int x = __builtin_bit_cast(int, v);
    int y = __builtin_amdgcn_update_dpp(x, x, CTRL, 0xF, 0xF, false);
    return v + __builtin_bit_cast(float, y);
}

__device__ __forceinline__ float wave_allsum64(float v) {
    v = dpp_add<0xB1>(v);    // quad_perm [1,0,3,2]
    v = dpp_add<0x4E>(v);    // quad_perm [2,3,0,1]
    v = dpp_add<0x141>(v);   // row_half_mirror -> 8-sum
    v = dpp_add<0x140>(v);   // row_mirror      -> 16-sum
    int x = __builtin_bit_cast(int, v);
    int y = __builtin_amdgcn_ds_swizzle(x, 0x401F);   // xor16 -> 32-sum
    v += __builtin_bit_cast(float, y);
    v += __shfl_xor(v, 32, 64);                        // -> 64-sum
    return v;
}

__device__ __forceinline__ float wave_sum64_shfl(float v) {
#pragma unroll
    for (int m = 32; m >= 1; m >>= 1) v += __shfl_xor(v, m, 64);
    return v;
}

// ---------- transpose pass: pose[b,i,p,q]->poseT[b,i,q,p]; T[i,o,p,s]->TT[i,o,s,p] ----------
__global__ __launch_bounds__(256) void transpose_kernel(
    const float* __restrict__ pose, const float* __restrict__ trans,
    float* __restrict__ poseT, float* __restrict__ TT)
{
    const int idx  = blockIdx.x * 256 + threadIdx.x;    // < 4194304
    const int lane = idx & 63;
    const int row  = idx >> 6;
    const int p    = lane >> 3;
    const int c    = lane & 7;
    TT[(row << 6) + c * 8 + p] = trans[idx];
    if (idx < B_ * CI_ * QS)
        poseT[(row << 6) + c * 8 + p] = pose[idx];
}

// ---------- fused 3-iteration EM, V register-cached (64/lane, 256-VGPR budget) ----------
// One block per (b,o): 8 waves, wave w owns i in [w*64, w*64+64).
// amdgpu_waves_per_eu(2,4): allocator budget 256 VGPR (no spill for V[64]),
// max 4 waves/EU -> two 8-wave blocks co-resident per CU.
__global__
__attribute__((amdgpu_flat_work_group_size(512, 512), amdgpu_waves_per_eu(2, 4)))
void capsule_kernel(
    const float* __restrict__ poseT,   // [B,CI,q,p]
    const float* __restrict__ TT,      // [CI,CO,s,p]
    const float* __restrict__ act,
    const float* __restrict__ bias_a,
    const float* __restrict__ bias_b,
    float* __restrict__ logits,
    float* __restrict__ mu_out)
{
    // XCD-aware swizzle: 16 o's pinned per XCD so its TT slice stays L2-hot.
    const int blk = blockIdx.x;
    const int xcd = blk & 7;
    const int idx = blk >> 3;                 // 0..255
    const int o   = xcd + ((idx & 15) << 3);
    const int b   = idx >> 4;

    const int tid  = threadIdx.x;
    const int wave = tid >> 6;
    const int lane = tid & 63;
    const int q    = lane >> 3;
    const int s    = lane & 7;
    const int i0   = wave * IPW;

    const float4* pT4  = (const float4*)poseT + ((size_t)(b * CI_ + i0)) * 16 + q * 2;
    const float4* tT4  = (const float4*)TT    + ((size_t)(i0 * CO_ + o)) * 16 + s * 2;
    const float*  actb = act + b * CI_ + i0;

    __shared__ float sA[NWAVE][QS];
    __shared__ float sB[NWAVE][QS];
    __shared__ float sC[NWAVE];

    float V[IPW];
    float Sw = 0.f, SwV = 0.f, SwV2 = 0.f;

    // sweep 1: fill V + act-weighted moments (w_i = act_i; R=1/CO cancels)
#pragma unroll 8
    for (int j = 0; j < IPW; ++j) {
        float4 a0 = pT4[j * 16];
        float4 a1 = pT4[j * 16 + 1];
        float4 b0 = tT4[(size_t)j * (CO_ * 16)];
        float4 b1 = tT4[(size_t)j * (CO_ * 16) + 1];
        float v;
        v = a0.x * b0.x;
        v = fmaf(a0.y, b0.y, v);
        v = fmaf(a0.z, b0.z, v);
        v = fmaf(a0.w, b0.w, v);
        v = fmaf(a1.x, b1.x, v);
        v = fmaf(a1.y, b1.y, v);
        v = fmaf(a1.z, b1.z, v);
        v = fmaf(a1.w, b1.w, v);
        V[j] = v;
        float ai = actb[j];
        Sw  += ai;
        SwV  = fmaf(ai, v, SwV);
        SwV2 = fmaf(ai * v, v, SwV2);
    }

    auto block_reduce = [&]() {
        __syncthreads();                       // protect previous round's reads
        sA[wave][lane] = SwV;
        sB[wave][lane] = SwV2;
        if (lane == 0) sC[wave] = Sw;
        __syncthreads();
        float a = 0.f, bb = 0.f, c = 0.f;
#pragma unroll
        for (int w = 0; w < NWAVE; ++w) {
            a  += sA[w][lane];
            bb += sB[w][lane];
            c  += sC[w];
        }
        SwV = a; SwV2 = bb; Sw = c;
    };

    block_reduce();
    float invSw = (Sw != 0.f) ? 1.f / Sw : 0.f;
    float mu  = SwV * invSw;
    float var = fmaxf(fmaf(-mu, mu, SwV2 * invSw), 1e-30f);
    float is  = 1.f / sqrtf(var);

    // sweeps 2,3: w_i = act_i * P_i; P_i = sum_qs is*exp(-0.5*((V-mu)*is)^2)
    // (act_out, global L1 norm, 1/sqrt(2pi) all cancel in r — validated R3==R4)
#pragma unroll 1
    for (int it = 0; it < 2; ++it) {
        const float is2c = is * is * NEG_HALF_LOG2E;
        Sw = 0.f; SwV = 0.f; SwV2 = 0.f;
#pragma unroll 8
        for (int j = 0; j < IPW; ++j) {
            float v   = V[j];
            float d   = v - mu;
            float arg = d * d * is2c;
            float pr  = is * exp2f(arg);
            float P   = wave_allsum64(pr);
            float w   = actb[j] * P;
            Sw  += w;
            SwV  = fmaf(w, v, SwV);
            SwV2 = fmaf(w * v, v, SwV2);
        }
        block_reduce();
        invSw = (Sw != 0.f) ? 1.f / Sw : 0.f;
        mu  = SwV * invSw;
        var = fmaxf(fmaf(-mu, mu, SwV2 * invSw), 1e-30f);
        is  = 1.f / sqrtf(var);
    }

    if (wave == 0) {
        mu_out[((size_t)b * CO_ + o) * QS + lane] = mu;
        // logits = LAMB*(bias_a - bias_b*1 - sum_qs 0.5*log var) + softmax-inv const
        float sl = wave_sum64_shfl(0.5f * logf(var));
        if (lane == 0)
            logits[b * CO_ + o] = LAMB * (bias_a[o] - bias_b[o] - sl);
    }
}

// ---------- legacy path (R9, proven): used only if ws_size is too small ----------
__global__ __launch_bounds__(256, 4) void capsule_legacy(
    const float* __restrict__ pose,
    const float* __restrict__ trans,
    const float* __restrict__ act,
    const float* __restrict__ bias_a,
    const float* __restrict__ bias_b,
    float* __restrict__ logits,
    float* __restrict__ mu_out)
{
    const int blk  = blockIdx.x;
    const int b    = blk >> 7;
    const int o    = blk & 127;
    const int tid  = threadIdx.x;
    const int wave = tid >> 6;
    const int lane = tid & 63;
    const int q    = lane >> 3;
    const int s    = lane & 7;
    const int i0   = wave * 128;

    const float* poseb = pose + ((size_t)b * CI_ + i0) * QS + lane;
    const float* tb    = trans + ((size_t)i0 * CO_ + o) * QS + lane;
    const float* actb  = act + b * CI_ + i0;

    __shared__ float sSwV[4][QS];
    __shared__ float sSwV2[4][QS];
    __shared__ float sSw[4];

    float Sw = 0.f, SwV = 0.f, SwV2 = 0.f;

    auto do_sweep = [&](bool use_prob, float mu_r, float is_r) {
        Sw = 0.f; SwV = 0.f; SwV2 = 0.f;
        for (int j = 0; j < 128; ++j) {
            float pe = poseb[(size_t)j * QS];
            float te = tb[(size_t)j * (CO_ * QS)];
            float ai = actb[j];
            float V = 0.f;
#pragma unroll
            for (int p = 0; p < 8; ++p) {
                float a = __shfl(pe, p * 8 + q, 64);
                float t = __shfl(te, p * 8 + s, 64);
                V = fmaf(a, t, V);
            }
            float w;
            if (use_prob) {
                float d  = V - mu_r;
                float e  = d * is_r;
                float pr = is_r * exp2f(e * e * NEG_HALF_LOG2E);
                w = ai * wave_sum64_shfl(pr);
            } else {
                w = ai;
            }
            Sw += w;
            SwV  = fmaf(w, V, SwV);
            SwV2 = fmaf(w * V, V, SwV2);
        }
        __syncthreads();
        sSwV[wave][lane]  = SwV;
        sSwV2[wave][lane] = SwV2;
        if (lane == 0) sSw[wave] = Sw;
        __syncthreads();
        float a = 0.f, c = 0.f, d2 = 0.f;
#pragma unroll
        for (int w2 = 0; w2 < 4; ++w2) {
            a  += sSwV[w2][lane];
            d2 += sSwV2[w2][lane];
            c  += sSw[w2];
        }
        SwV = a; SwV2 = d2; Sw = c;
    };

    float mu = 0.f, var = 1.f, is = 1.f;
    do_sweep(false, 0.f, 0.f);
    {
        float invSw = (Sw != 0.f) ? 1.f / Sw : 0.f;
        mu = SwV * invSw; var = fmaxf(fmaf(-mu, mu, SwV2 * invSw), 1e-30f);
        is = 1.f / sqrtf(var);
    }
    do_sweep(true, mu, is);
    {
        float invSw = (Sw != 0.f) ? 1.f / Sw : 0.f;
        mu = SwV * invSw; var = fmaxf(fmaf(-mu, mu, SwV2 * invSw), 1e-30f);
        is = 1.f / sqrtf(var);
    }
    do_sweep(true, mu, is);
    {
        float invSw = (Sw != 0.f) ? 1.f / Sw : 0.f;
        mu = SwV * invSw; var = fmaxf(fmaf(-mu, mu, SwV2 * invSw), 1e-30f);
    }

    if (wave == 0) {
        mu_out[((size_t)b * CO_ + o) * QS + lane] = mu;
        float sl = wave_sum64_shfl(0.5f * logf(var));
        if (lane == 0)
            logits[b * CO_ + o] = LAMB * (bias_a[o] - bias_b[o] - sl);
    }
}

__global__ __launch_bounds__(128) void softmax_kernel(
    const float* __restrict__ logits, float* __restrict__ out)
{
    const int b = blockIdx.x;
    const int t = threadIdx.x;
    float l = logits[b * CO_ + t];

    __shared__ float sm[2];
    __shared__ float s2[2];

    float m = l;
#pragma unroll
    for (int k = 32; k >= 1; k >>= 1) m = fmaxf(m, __shfl_xor(m, k, 64));
    if ((t & 63) == 0) sm[t >> 6] = m;
    __syncthreads();
    m = fmaxf(sm[0], sm[1]);

    float e = expf(l - m);
    float ssum = e;
#pragma unroll
    for (int k = 32; k >= 1; k >>= 1) ssum += __shfl_xor(ssum, k, 64);
    if ((t & 63) == 0) s2[t >> 6] = ssum;
    __syncthreads();
    float tot = s2[0] + s2[1];

    out[b * CO_ + t] = e / tot;
}

extern "C" void kernel_launch(void* const* d_in, const int* in_sizes, int n_in,
                              void* d_out, int out_size, void* d_ws, size_t ws_size,
                              hipStream_t stream) {
    // Size-keyed binding (no-op under documented order; sizes are all distinct).
    const float *act = nullptr, *pose = nullptr, *trans = nullptr;
    const float *bias_a = nullptr, *bias_b = nullptr;
    for (int i = 0; i < n_in; ++i) {
        const float* p = (const float*)d_in[i];
        switch (in_sizes[i]) {
            case 8192:    act = p; break;
            case 524288:  pose = p; break;
            case 4194304: trans = p; break;
            case 128:     if (!bias_a) bias_a = p; else bias_b = p; break;
            default: break;
        }
    }
    if (!act || !pose || !trans || !bias_a || !bias_b) {
        act    = (const float*)d_in[0];
        pose   = (const float*)d_in[1];
        trans  = (const float*)d_in[2];
        bias_a = (const float*)d_in[3];
        bias_b = (const float*)d_in[4];
    }

    float* out_act = (float*)d_out;                // f32 [16,128]
    float* out_mu  = out_act + B_ * CO_;           // f32 [16,128,8,8]

    const size_t NEEDED = (size_t)(524288 + 4194304 + 2048) * 4;   // ~18.9 MB

    if (ws_size >= NEEDED) {
        float* poseT  = (float*)d_ws;              // 524288
        float* TT     = poseT + 524288;            // 4194304
        float* logits = TT + 4194304;              // 2048

        transpose_kernel<<<dim3(4194304 / 256), dim3(256), 0, stream>>>(
            pose, trans, poseT, TT);
        capsule_kernel<<<dim3(B_ * CO_), dim3(512), 0, stream>>>(
            poseT, TT, act, bias_a, bias_b, logits, out_mu);
        softmax_kernel<<<dim3(B_), dim3(128), 0, stream>>>(logits, out_act);
    } else {
        float* logits = (float*)d_ws;              // 2048 floats
        capsule_legacy<<<dim3(B_ * CO_), dim3(256), 0, stream>>>(
            pose, trans, act, bias_a, bias_b, logits, out_mu);
        softmax_kernel<<<dim3(B_), dim3(128), 0, stream>>>(logits, out_act);
    }
}

// Round 13
// 344.748 us; speedup vs baseline: 1.1198x; 1.1198x over previous
//
#include <hip/hip_runtime.h>
#include <hip/hip_bf16.h>

#define B_    16
#define CI_   512
#define CO_   128
#define QS    64
#define NWAVE 8
#define IPW   (CI_ / NWAVE)   // 64 capsules_in per wave

static constexpr float LAMB = 0.2f;
// exp(-0.5*x) == exp2f(x * NEG_HALF_LOG2E)
static constexpr float NEG_HALF_LOG2E = -0.72134752044448170368f;

// ---------- wave reduction: DPP (VALU pipe) intra-16, swizzle/shfl for 16/32 ----------
template <int CTRL>
__device__ __forceinline__ float dpp_add(float v) {
    int x = __builtin_bit_cast(int, v);
    int y = __builtin_amdgcn_update_dpp(x, x, CTRL, 0xF, 0xF, false);
    return v + __builtin_bit_cast(float, y);
}

__device__ __forceinline__ float wave_allsum64(float v) {
    v = dpp_add<0xB1>(v);    // quad_perm [1,0,3,2]
    v = dpp_add<0x4E>(v);    // quad_perm [2,3,0,1]
    v = dpp_add<0x141>(v);   // row_half_mirror -> 8-sum
    v = dpp_add<0x140>(v);   // row_mirror      -> 16-sum
    int x = __builtin_bit_cast(int, v);
    int y = __builtin_amdgcn_ds_swizzle(x, 0x401F);   // xor16 -> 32-sum
    v += __builtin_bit_cast(float, y);
    v += __shfl_xor(v, 32, 64);                        // -> 64-sum
    return v;
}

__device__ __forceinline__ float wave_sum64_shfl(float v) {
#pragma unroll
    for (int m = 32; m >= 1; m >>= 1) v += __shfl_xor(v, m, 64);
    return v;
}

// ---------- transpose pass: pose[b,i,p,q]->poseT[b,i,q,p]; T[i,o,p,s]->TT[i,o,s,p] ----------
__global__ __launch_bounds__(256) void transpose_kernel(
    const float* __restrict__ pose, const float* __restrict__ trans,
    float* __restrict__ poseT, float* __restrict__ TT)
{
    const int idx  = blockIdx.x * 256 + threadIdx.x;    // < 4194304
    const int lane = idx & 63;
    const int row  = idx >> 6;
    const int p    = lane >> 3;
    const int c    = lane & 7;
    TT[(row << 6) + c * 8 + p] = trans[idx];
    if (idx < B_ * CI_ * QS)
        poseT[(row << 6) + c * 8 + p] = pose[idx];
}

// ---------- fused 3-iteration EM, V register-cached (64/lane) ----------
// One block per (b,o): 8 waves, wave w owns i in [w*64, w*64+64).
// FULL unroll on every V-loop: compile-time indices -> SROA promotes V[] to
// registers (R12's `unroll 8` broke this -> 256 MB scratch traffic).
// waves_per_eu(2,4): VGPR cap >=128 so V[64]+live values fit without spill;
// 8-wave blocks at <=4 waves/EU -> 2 blocks/CU co-resident.
__global__
__attribute__((amdgpu_flat_work_group_size(512, 512), amdgpu_waves_per_eu(2, 4)))
void capsule_kernel(
    const float* __restrict__ poseT,   // [B,CI,q,p]
    const float* __restrict__ TT,      // [CI,CO,s,p]
    const float* __restrict__ act,
    const float* __restrict__ bias_a,
    const float* __restrict__ bias_b,
    float* __restrict__ logits,
    float* __restrict__ mu_out)
{
    // XCD-aware swizzle: 16 o's pinned per XCD so its TT slice stays L2-hot.
    const int blk = blockIdx.x;
    const int xcd = blk & 7;
    const int idx = blk >> 3;                 // 0..255
    const int o   = xcd + ((idx & 15) << 3);
    const int b   = idx >> 4;

    const int tid  = threadIdx.x;
    const int wave = tid >> 6;
    const int lane = tid & 63;
    const int q    = lane >> 3;
    const int s    = lane & 7;
    const int i0   = wave * IPW;

    const float4* pT4  = (const float4*)poseT + ((size_t)(b * CI_ + i0)) * 16 + q * 2;
    const float4* tT4  = (const float4*)TT    + ((size_t)(i0 * CO_ + o)) * 16 + s * 2;
    const float*  actb = act + b * CI_ + i0;

    __shared__ float sA[NWAVE][QS];
    __shared__ float sB[NWAVE][QS];
    __shared__ float sC[NWAVE];

    float V[IPW];
    float Sw = 0.f, SwV = 0.f, SwV2 = 0.f;

    // sweep 1: fill V + act-weighted moments (w_i = act_i; R=1/CO cancels)
#pragma unroll
    for (int j = 0; j < IPW; ++j) {
        float4 a0 = pT4[j * 16];
        float4 a1 = pT4[j * 16 + 1];
        float4 b0 = tT4[(size_t)j * (CO_ * 16)];
        float4 b1 = tT4[(size_t)j * (CO_ * 16) + 1];
        float v;
        v = a0.x * b0.x;
        v = fmaf(a0.y, b0.y, v);
        v = fmaf(a0.z, b0.z, v);
        v = fmaf(a0.w, b0.w, v);
        v = fmaf(a1.x, b1.x, v);
        v = fmaf(a1.y, b1.y, v);
        v = fmaf(a1.z, b1.z, v);
        v = fmaf(a1.w, b1.w, v);
        V[j] = v;
        float ai = actb[j];
        Sw  += ai;
        SwV  = fmaf(ai, v, SwV);
        SwV2 = fmaf(ai * v, v, SwV2);
    }

    auto block_reduce = [&]() {
        __syncthreads();                       // protect previous round's reads
        sA[wave][lane] = SwV;
        sB[wave][lane] = SwV2;
        if (lane == 0) sC[wave] = Sw;
        __syncthreads();
        float a = 0.f, bb = 0.f, c = 0.f;
#pragma unroll
        for (int w = 0; w < NWAVE; ++w) {
            a  += sA[w][lane];
            bb += sB[w][lane];
            c  += sC[w];
        }
        SwV = a; SwV2 = bb; Sw = c;
    };

    block_reduce();
    float invSw = (Sw != 0.f) ? 1.f / Sw : 0.f;
    float mu  = SwV * invSw;
    float var = fmaxf(fmaf(-mu, mu, SwV2 * invSw), 1e-30f);
    float is  = 1.f / sqrtf(var);

    // sweeps 2,3: w_i = act_i * P_i; P_i = sum_qs is*exp(-0.5*((V-mu)*is)^2)
    // (act_out, global L1 norm, 1/sqrt(2pi) all cancel in r — validated R3==R4)
#pragma unroll 1
    for (int it = 0; it < 2; ++it) {
        const float is2c = is * is * NEG_HALF_LOG2E;
        Sw = 0.f; SwV = 0.f; SwV2 = 0.f;
#pragma unroll
        for (int j = 0; j < IPW; ++j) {
            float v   = V[j];
            float d   = v - mu;
            float arg = d * d * is2c;
            float pr  = is * exp2f(arg);
            float P   = wave_allsum64(pr);
            float w   = actb[j] * P;
            Sw  += w;
            SwV  = fmaf(w, v, SwV);
            SwV2 = fmaf(w * v, v, SwV2);
        }
        block_reduce();
        invSw = (Sw != 0.f) ? 1.f / Sw : 0.f;
        mu  = SwV * invSw;
        var = fmaxf(fmaf(-mu, mu, SwV2 * invSw), 1e-30f);
        is  = 1.f / sqrtf(var);
    }

    if (wave == 0) {
        mu_out[((size_t)b * CO_ + o) * QS + lane] = mu;
        // logits = LAMB*(bias_a - bias_b*1 - sum_qs 0.5*log var) + softmax-inv const
        float sl = wave_sum64_shfl(0.5f * logf(var));
        if (lane == 0)
            logits[b * CO_ + o] = LAMB * (bias_a[o] - bias_b[o] - sl);
    }
}

// ---------- legacy path (R9, proven): used only if ws_size is too small ----------
__global__ __launch_bounds__(256, 4) void capsule_legacy(
    const float* __restrict__ pose,
    const float* __restrict__ trans,
    const float* __restrict__ act,
    const float* __restrict__ bias_a,
    const float* __restrict__ bias_b,
    float* __restrict__ logits,
    float* __restrict__ mu_out)
{
    const int blk  = blockIdx.x;
    const int b    = blk >> 7;
    const int o    = blk & 127;
    const int tid  = threadIdx.x;
    const int wave = tid >> 6;
    const int lane = tid & 63;
    const int q    = lane >> 3;
    const int s    = lane & 7;
    const int i0   = wave * 128;

    const float* poseb = pose + ((size_t)b * CI_ + i0) * QS + lane;
    const float* tb    = trans + ((size_t)i0 * CO_ + o) * QS + lane;
    const float* actb  = act + b * CI_ + i0;

    __shared__ float sSwV[4][QS];
    __shared__ float sSwV2[4][QS];
    __shared__ float sSw[4];

    float Sw = 0.f, SwV = 0.f, SwV2 = 0.f;

    auto do_sweep = [&](bool use_prob, float mu_r, float is_r) {
        Sw = 0.f; SwV = 0.f; SwV2 = 0.f;
        for (int j = 0; j < 128; ++j) {
            float pe = poseb[(size_t)j * QS];
            float te = tb[(size_t)j * (CO_ * QS)];
            float ai = actb[j];
            float V = 0.f;
#pragma unroll
            for (int p = 0; p < 8; ++p) {
                float a = __shfl(pe, p * 8 + q, 64);
                float t = __shfl(te, p * 8 + s, 64);
                V = fmaf(a, t, V);
            }
            float w;
            if (use_prob) {
                float d  = V - mu_r;
                float e  = d * is_r;
                float pr = is_r * exp2f(e * e * NEG_HALF_LOG2E);
                w = ai * wave_sum64_shfl(pr);
            } else {
                w = ai;
            }
            Sw += w;
            SwV  = fmaf(w, V, SwV);
            SwV2 = fmaf(w * V, V, SwV2);
        }
        __syncthreads();
        sSwV[wave][lane]  = SwV;
        sSwV2[wave][lane] = SwV2;
        if (lane == 0) sSw[wave] = Sw;
        __syncthreads();
        float a = 0.f, c = 0.f, d2 = 0.f;
#pragma unroll
        for (int w2 = 0; w2 < 4; ++w2) {
            a  += sSwV[w2][lane];
            d2 += sSwV2[w2][lane];
            c  += sSw[w2];
        }
        SwV = a; SwV2 = d2; Sw = c;
    };

    float mu = 0.f, var = 1.f, is = 1.f;
    do_sweep(false, 0.f, 0.f);
    {
        float invSw = (Sw != 0.f) ? 1.f / Sw : 0.f;
        mu = SwV * invSw; var = fmaxf(fmaf(-mu, mu, SwV2 * invSw), 1e-30f);
        is = 1.f / sqrtf(var);
    }
    do_sweep(true, mu, is);
    {
        float invSw = (Sw != 0.f) ? 1.f / Sw : 0.f;
        mu = SwV * invSw; var = fmaxf(fmaf(-mu, mu, SwV2 * invSw), 1e-30f);
        is = 1.f / sqrtf(var);
    }
    do_sweep(true, mu, is);
    {
        float invSw = (Sw != 0.f) ? 1.f / Sw : 0.f;
        mu = SwV * invSw; var = fmaxf(fmaf(-mu, mu, SwV2 * invSw), 1e-30f);
    }

    if (wave == 0) {
        mu_out[((size_t)b * CO_ + o) * QS + lane] = mu;
        float sl = wave_sum64_shfl(0.5f * logf(var));
        if (lane == 0)
            logits[b * CO_ + o] = LAMB * (bias_a[o] - bias_b[o] - sl);
    }
}

__global__ __launch_bounds__(128) void softmax_kernel(
    const float* __restrict__ logits, float* __restrict__ out)
{
    const int b = blockIdx.x;
    const int t = threadIdx.x;
    float l = logits[b * CO_ + t];

    __shared__ float sm[2];
    __shared__ float s2[2];

    float m = l;
#pragma unroll
    for (int k = 32; k >= 1; k >>= 1) m = fmaxf(m, __shfl_xor(m, k, 64));
    if ((t & 63) == 0) sm[t >> 6] = m;
    __syncthreads();
    m = fmaxf(sm[0], sm[1]);

    float e = expf(l - m);
    float ssum = e;
#pragma unroll
    for (int k = 32; k >= 1; k >>= 1) ssum += __shfl_xor(ssum, k, 64);
    if ((t & 63) == 0) s2[t >> 6] = ssum;
    __syncthreads();
    float tot = s2[0] + s2[1];

    out[b * CO_ + t] = e / tot;
}

extern "C" void kernel_launch(void* const* d_in, const int* in_sizes, int n_in,
                              void* d_out, int out_size, void* d_ws, size_t ws_size,
                              hipStream_t stream) {
    // Size-keyed binding (no-op under documented order; sizes are all distinct).
    const float *act = nullptr, *pose = nullptr, *trans = nullptr;
    const float *bias_a = nullptr, *bias_b = nullptr;
    for (int i = 0; i < n_in; ++i) {
        const float* p = (const float*)d_in[i];
        switch (in_sizes[i]) {
            case 8192:    act = p; break;
            case 524288:  pose = p; break;
            case 4194304: trans = p; break;
            case 128:     if (!bias_a) bias_a = p; else bias_b = p; break;
            default: break;
        }
    }
    if (!act || !pose || !trans || !bias_a || !bias_b) {
        act    = (const float*)d_in[0];
        pose   = (const float*)d_in[1];
        trans  = (const float*)d_in[2];
        bias_a = (const float*)d_in[3];
        bias_b = (const float*)d_in[4];
    }

    float* out_act = (float*)d_out;                // f32 [16,128]
    float* out_mu  = out_act + B_ * CO_;           // f32 [16,128,8,8]

    const size_t NEEDED = (size_t)(524288 + 4194304 + 2048) * 4;   // ~18.9 MB

    if (ws_size >= NEEDED) {
        float* poseT  = (float*)d_ws;              // 524288
        float* TT     = poseT + 524288;            // 4194304
        float* logits = TT + 4194304;              // 2048

        transpose_kernel<<<dim3(4194304 / 256), dim3(256), 0, stream>>>(
            pose, trans, poseT, TT);
        capsule_kernel<<<dim3(B_ * CO_), dim3(512), 0, stream>>>(
            poseT, TT, act, bias_a, bias_b, logits, out_mu);
        softmax_kernel<<<dim3(B_), dim3(128), 0, stream>>>(logits, out_act);
    } else {
        float* logits = (float*)d_ws;              // 2048 floats
        capsule_legacy<<<dim3(B_ * CO_), dim3(256), 0, stream>>>(
            pose, trans, act, bias_a, bias_b, logits, out_mu);
        softmax_kernel<<<dim3(B_), dim3(128), 0, stream>>>(logits, out_act);
    }
}

// Round 14
// 330.138 us; speedup vs baseline: 1.1694x; 1.0443x over previous
//
#include <hip/hip_runtime.h>
#include <hip/hip_bf16.h>

#define B_    16
#define CI_   512
#define CO_   128
#define QS    64
#define NWAVE 16
#define IPW   (CI_ / NWAVE)   // 32 capsules_in per wave

static constexpr float LAMB = 0.2f;
// exp(-0.5*x) == exp2f(x * NEG_HALF_LOG2E)
static constexpr float NEG_HALF_LOG2E = -0.72134752044448170368f;

// ---------- wave reduction: DPP (VALU pipe) intra-16, swizzle/shfl for 16/32 ----------
template <int CTRL>
__device__ __forceinline__ float dpp_add(float v) {
    int x = __builtin_bit_cast(int, v);
    int y = __builtin_amdgcn_update_dpp(x, x, CTRL, 0xF, 0xF, false);
    return v + __builtin_bit_cast(float, y);
}

__device__ __forceinline__ float wave_allsum64(float v) {
    v = dpp_add<0xB1>(v);    // quad_perm [1,0,3,2]
    v = dpp_add<0x4E>(v);    // quad_perm [2,3,0,1]
    v = dpp_add<0x141>(v);   // row_half_mirror -> 8-sum
    v = dpp_add<0x140>(v);   // row_mirror      -> 16-sum
    int x = __builtin_bit_cast(int, v);
    int y = __builtin_amdgcn_ds_swizzle(x, 0x401F);   // xor16 -> 32-sum
    v += __builtin_bit_cast(float, y);
    v += __shfl_xor(v, 32, 64);                        // -> 64-sum
    return v;
}

__device__ __forceinline__ float wave_sum64_shfl(float v) {
#pragma unroll
    for (int m = 32; m >= 1; m >>= 1) v += __shfl_xor(v, m, 64);
    return v;
}

// ---------- transpose pass: pose[b,i,p,q]->poseT[b,i,q,p]; T[i,o,p,s]->TT[i,o,s,p] ----------
__global__ __launch_bounds__(256) void transpose_kernel(
    const float* __restrict__ pose, const float* __restrict__ trans,
    float* __restrict__ poseT, float* __restrict__ TT)
{
    const int idx  = blockIdx.x * 256 + threadIdx.x;    // < 4194304
    const int lane = idx & 63;
    const int row  = idx >> 6;
    const int p    = lane >> 3;
    const int c    = lane & 7;
    TT[(row << 6) + c * 8 + p] = trans[idx];
    if (idx < B_ * CI_ * QS)
        poseT[(row << 6) + c * 8 + p] = pose[idx];
}

// ---------- fused 3-iteration EM, V register-cached (32/lane) ----------
// One block per (b,o): 16 waves, wave w owns i in [w*32, w*32+32).
// 1024-thr block => 16 wave slots required => 4 waves/EU resident (R11 showed
// this shape's TLP beats 8-wave blocks even WITH spill). waves_per_eu(4,4)
// pins the VGPR budget to 128: V[32]+~50 working regs fit with zero spill
// (R11's heuristic chose 64+spill; R13 proved pinning works). Full unroll
// everywhere: R12 proved partial unroll -> runtime-indexed V[] -> scratch.
__global__
__attribute__((amdgpu_flat_work_group_size(1024, 1024), amdgpu_waves_per_eu(4, 4)))
void capsule_kernel(
    const float* __restrict__ poseT,   // [B,CI,q,p]
    const float* __restrict__ TT,      // [CI,CO,s,p]
    const float* __restrict__ act,
    const float* __restrict__ bias_a,
    const float* __restrict__ bias_b,
    float* __restrict__ logits,
    float* __restrict__ mu_out)
{
    // XCD-aware swizzle: 16 o's pinned per XCD so its TT slice stays L2-hot.
    const int blk = blockIdx.x;
    const int xcd = blk & 7;
    const int idx = blk >> 3;                 // 0..255
    const int o   = xcd + ((idx & 15) << 3);
    const int b   = idx >> 4;

    const int tid  = threadIdx.x;
    const int wave = tid >> 6;
    const int lane = tid & 63;
    const int q    = lane >> 3;
    const int s    = lane & 7;
    const int i0   = wave * IPW;

    const float4* pT4  = (const float4*)poseT + ((size_t)(b * CI_ + i0)) * 16 + q * 2;
    const float4* tT4  = (const float4*)TT    + ((size_t)(i0 * CO_ + o)) * 16 + s * 2;
    const float*  actb = act + b * CI_ + i0;

    __shared__ float sA[NWAVE][QS];
    __shared__ float sB[NWAVE][QS];
    __shared__ float sC[NWAVE];

    float V[IPW];
    float Sw = 0.f, SwV = 0.f, SwV2 = 0.f;

    // sweep 1: fill V + act-weighted moments (w_i = act_i; R=1/CO cancels)
#pragma unroll
    for (int j = 0; j < IPW; ++j) {
        float4 a0 = pT4[j * 16];
        float4 a1 = pT4[j * 16 + 1];
        float4 b0 = tT4[(size_t)j * (CO_ * 16)];
        float4 b1 = tT4[(size_t)j * (CO_ * 16) + 1];
        float v;
        v = a0.x * b0.x;
        v = fmaf(a0.y, b0.y, v);
        v = fmaf(a0.z, b0.z, v);
        v = fmaf(a0.w, b0.w, v);
        v = fmaf(a1.x, b1.x, v);
        v = fmaf(a1.y, b1.y, v);
        v = fmaf(a1.z, b1.z, v);
        v = fmaf(a1.w, b1.w, v);
        V[j] = v;
        float ai = actb[j];
        Sw  += ai;
        SwV  = fmaf(ai, v, SwV);
        SwV2 = fmaf(ai * v, v, SwV2);
    }

    auto block_reduce = [&]() {
        __syncthreads();                       // protect previous round's reads
        sA[wave][lane] = SwV;
        sB[wave][lane] = SwV2;
        if (lane == 0) sC[wave] = Sw;
        __syncthreads();
        float a = 0.f, bb = 0.f, c = 0.f;
#pragma unroll
        for (int w = 0; w < NWAVE; ++w) {
            a  += sA[w][lane];
            bb += sB[w][lane];
            c  += sC[w];
        }
        SwV = a; SwV2 = bb; Sw = c;
    };

    block_reduce();
    float invSw = (Sw != 0.f) ? 1.f / Sw : 0.f;
    float mu  = SwV * invSw;
    float var = fmaxf(fmaf(-mu, mu, SwV2 * invSw), 1e-30f);
    float is  = 1.f / sqrtf(var);

    // sweeps 2,3: w_i = act_i * P_i; P_i = sum_qs is*exp(-0.5*((V-mu)*is)^2)
    // (act_out, global L1 norm, 1/sqrt(2pi) all cancel in r — validated R3==R4)
#pragma unroll 1
    for (int it = 0; it < 2; ++it) {
        const float is2c = is * is * NEG_HALF_LOG2E;
        Sw = 0.f; SwV = 0.f; SwV2 = 0.f;
#pragma unroll
        for (int j = 0; j < IPW; ++j) {
            float v   = V[j];
            float d   = v - mu;
            float arg = d * d * is2c;
            float pr  = is * exp2f(arg);
            float P   = wave_allsum64(pr);
            float w   = actb[j] * P;
            Sw  += w;
            SwV  = fmaf(w, v, SwV);
            SwV2 = fmaf(w * v, v, SwV2);
        }
        block_reduce();
        invSw = (Sw != 0.f) ? 1.f / Sw : 0.f;
        mu  = SwV * invSw;
        var = fmaxf(fmaf(-mu, mu, SwV2 * invSw), 1e-30f);
        is  = 1.f / sqrtf(var);
    }

    if (wave == 0) {
        mu_out[((size_t)b * CO_ + o) * QS + lane] = mu;
        // logits = LAMB*(bias_a - bias_b*1 - sum_qs 0.5*log var) + softmax-inv const
        float sl = wave_sum64_shfl(0.5f * logf(var));
        if (lane == 0)
            logits[b * CO_ + o] = LAMB * (bias_a[o] - bias_b[o] - sl);
    }
}

// ---------- legacy path (R9, proven): used only if ws_size is too small ----------
__global__ __launch_bounds__(256, 4) void capsule_legacy(
    const float* __restrict__ pose,
    const float* __restrict__ trans,
    const float* __restrict__ act,
    const float* __restrict__ bias_a,
    const float* __restrict__ bias_b,
    float* __restrict__ logits,
    float* __restrict__ mu_out)
{
    const int blk  = blockIdx.x;
    const int b    = blk >> 7;
    const int o    = blk & 127;
    const int tid  = threadIdx.x;
    const int wave = tid >> 6;
    const int lane = tid & 63;
    const int q    = lane >> 3;
    const int s    = lane & 7;
    const int i0   = wave * 128;

    const float* poseb = pose + ((size_t)b * CI_ + i0) * QS + lane;
    const float* tb    = trans + ((size_t)i0 * CO_ + o) * QS + lane;
    const float* actb  = act + b * CI_ + i0;

    __shared__ float sSwV[4][QS];
    __shared__ float sSwV2[4][QS];
    __shared__ float sSw[4];

    float Sw = 0.f, SwV = 0.f, SwV2 = 0.f;

    auto do_sweep = [&](bool use_prob, float mu_r, float is_r) {
        Sw = 0.f; SwV = 0.f; SwV2 = 0.f;
        for (int j = 0; j < 128; ++j) {
            float pe = poseb[(size_t)j * QS];
            float te = tb[(size_t)j * (CO_ * QS)];
            float ai = actb[j];
            float V = 0.f;
#pragma unroll
            for (int p = 0; p < 8; ++p) {
                float a = __shfl(pe, p * 8 + q, 64);
                float t = __shfl(te, p * 8 + s, 64);
                V = fmaf(a, t, V);
            }
            float w;
            if (use_prob) {
                float d  = V - mu_r;
                float e  = d * is_r;
                float pr = is_r * exp2f(e * e * NEG_HALF_LOG2E);
                w = ai * wave_sum64_shfl(pr);
            } else {
                w = ai;
            }
            Sw += w;
            SwV  = fmaf(w, V, SwV);
            SwV2 = fmaf(w * V, V, SwV2);
        }
        __syncthreads();
        sSwV[wave][lane]  = SwV;
        sSwV2[wave][lane] = SwV2;
        if (lane == 0) sSw[wave] = Sw;
        __syncthreads();
        float a = 0.f, c = 0.f, d2 = 0.f;
#pragma unroll
        for (int w2 = 0; w2 < 4; ++w2) {
            a  += sSwV[w2][lane];
            d2 += sSwV2[w2][lane];
            c  += sSw[w2];
        }
        SwV = a; SwV2 = d2; Sw = c;
    };

    float mu = 0.f, var = 1.f, is = 1.f;
    do_sweep(false, 0.f, 0.f);
    {
        float invSw = (Sw != 0.f) ? 1.f / Sw : 0.f;
        mu = SwV * invSw; var = fmaxf(fmaf(-mu, mu, SwV2 * invSw), 1e-30f);
        is = 1.f / sqrtf(var);
    }
    do_sweep(true, mu, is);
    {
        float invSw = (Sw != 0.f) ? 1.f / Sw : 0.f;
        mu = SwV * invSw; var = fmaxf(fmaf(-mu, mu, SwV2 * invSw), 1e-30f);
        is = 1.f / sqrtf(var);
    }
    do_sweep(true, mu, is);
    {
        float invSw = (Sw != 0.f) ? 1.f / Sw : 0.f;
        mu = SwV * invSw; var = fmaxf(fmaf(-mu, mu, SwV2 * invSw), 1e-30f);
    }

    if (wave == 0) {
        mu_out[((size_t)b * CO_ + o) * QS + lane] = mu;
        float sl = wave_sum64_shfl(0.5f * logf(var));
        if (lane == 0)
            logits[b * CO_ + o] = LAMB * (bias_a[o] - bias_b[o] - sl);
    }
}

__global__ __launch_bounds__(128) void softmax_kernel(
    const float* __restrict__ logits, float* __restrict__ out)
{
    const int b = blockIdx.x;
    const int t = threadIdx.x;
    float l = logits[b * CO_ + t];

    __shared__ float sm[2];
    __shared__ float s2[2];

    float m = l;
#pragma unroll
    for (int k = 32; k >= 1; k >>= 1) m = fmaxf(m, __shfl_xor(m, k, 64));
    if ((t & 63) == 0) sm[t >> 6] = m;
    __syncthreads();
    m = fmaxf(sm[0], sm[1]);

    float e = expf(l - m);
    float ssum = e;
#pragma unroll
    for (int k = 32; k >= 1; k >>= 1) ssum += __shfl_xor(ssum, k, 64);
    if ((t & 63) == 0) s2[t >> 6] = ssum;
    __syncthreads();
    float tot = s2[0] + s2[1];

    out[b * CO_ + t] = e / tot;
}

extern "C" void kernel_launch(void* const* d_in, const int* in_sizes, int n_in,
                              void* d_out, int out_size, void* d_ws, size_t ws_size,
                              hipStream_t stream) {
    // Size-keyed binding (no-op under documented order; sizes are all distinct).
    const float *act = nullptr, *pose = nullptr, *trans = nullptr;
    const float *bias_a = nullptr, *bias_b = nullptr;
    for (int i = 0; i < n_in; ++i) {
        const float* p = (const float*)d_in[i];
        switch (in_sizes[i]) {
            case 8192:    act = p; break;
            case 524288:  pose = p; break;
            case 4194304: trans = p; break;
            case 128:     if (!bias_a) bias_a = p; else bias_b = p; break;
            default: break;
        }
    }
    if (!act || !pose || !trans || !bias_a || !bias_b) {
        act    = (const float*)d_in[0];
        pose   = (const float*)d_in[1];
        trans  = (const float*)d_in[2];
        bias_a = (const float*)d_in[3];
        bias_b = (const float*)d_in[4];
    }

    float* out_act = (float*)d_out;                // f32 [16,128]
    float* out_mu  = out_act + B_ * CO_;           // f32 [16,128,8,8]

    const size_t NEEDED = (size_t)(524288 + 4194304 + 2048) * 4;   // ~18.9 MB

    if (ws_size >= NEEDED) {
        float* poseT  = (float*)d_ws;              // 524288
        float* TT     = poseT + 524288;            // 4194304
        float* logits = TT + 4194304;              // 2048

        transpose_kernel<<<dim3(4194304 / 256), dim3(256), 0, stream>>>(
            pose, trans, poseT, TT);
        capsule_kernel<<<dim3(B_ * CO_), dim3(1024), 0, stream>>>(
            poseT, TT, act, bias_a, bias_b, logits, out_mu);
        softmax_kernel<<<dim3(B_), dim3(128), 0, stream>>>(logits, out_act);
    } else {
        float* logits = (float*)d_ws;              // 2048 floats
        capsule_legacy<<<dim3(B_ * CO_), dim3(256), 0, stream>>>(
            pose, trans, act, bias_a, bias_b, logits, out_mu);
        softmax_kernel<<<dim3(B_), dim3(128), 0, stream>>>(logits, out_act);
    }
}

// Round 15
// 274.784 us; speedup vs baseline: 1.4049x; 1.2014x over previous
//
#include <hip/hip_runtime.h>
#include <hip/hip_bf16.h>

#define B_    16
#define CI_   512
#define CO_   128
#define QS    64
#define NWAVE 16
#define IPW   (CI_ / NWAVE)   // 32 capsules_in per wave

static constexpr float LAMB = 0.2f;
// exp(-0.5*x) == exp2f(x * NEG_HALF_LOG2E)
static constexpr float NEG_HALF_LOG2E = -0.72134752044448170368f;

// ---------- DPP pair-sum (VALU pipe) ----------
template <int CTRL>
__device__ __forceinline__ float dpp_add(float v) {
    int x = __builtin_bit_cast(int, v);
    int y = __builtin_amdgcn_update_dpp(x, x, CTRL, 0xF, 0xF, false);
    return v + __builtin_bit_cast(float, y);
}

__device__ __forceinline__ float wave_sum64_shfl(float v) {
#pragma unroll
    for (int m = 32; m >= 1; m >>= 1) v += __shfl_xor(v, m, 64);
    return v;
}

// ---------- transpose pass: pose[b,i,p,q]->poseT[b,i,q,p]; T[i,o,p,s]->TT[i,o,s,p] ----------
__global__ __launch_bounds__(256) void transpose_kernel(
    const float* __restrict__ pose, const float* __restrict__ trans,
    float* __restrict__ poseT, float* __restrict__ TT)
{
    const int idx  = blockIdx.x * 256 + threadIdx.x;    // < 4194304
    const int lane = idx & 63;
    const int row  = idx >> 6;
    const int p    = lane >> 3;
    const int c    = lane & 7;
    TT[(row << 6) + c * 8 + p] = trans[idx];
    if (idx < B_ * CI_ * QS)
        poseT[(row << 6) + c * 8 + p] = pose[idx];
}

// ---------- fused 3-iteration EM ----------
// One block per (b,o): 16 waves, wave w owns i in [w*32, w*32+32).
// V register-cached (full unroll -> SROA; R12 proved partial unroll spills).
// Sweeps 2,3: per-j 64-lane butterflies replaced by a staged LDS-transpose
// multi-reduction (R14 showed issue-bound: 2x TLP gave 0 gain, so cut insts).
// The uniform 1/sigma factor in pr cancels in mu/var and is dropped.
__global__
__attribute__((amdgpu_flat_work_group_size(1024, 1024), amdgpu_waves_per_eu(4, 4)))
void capsule_kernel(
    const float* __restrict__ poseT,   // [B,CI,q,p]
    const float* __restrict__ TT,      // [CI,CO,s,p]
    const float* __restrict__ act,
    const float* __restrict__ bias_a,
    const float* __restrict__ bias_b,
    float* __restrict__ logits,
    float* __restrict__ mu_out)
{
    // XCD-aware swizzle: 16 o's pinned per XCD so its TT slice stays L2-hot.
    const int blk = blockIdx.x;
    const int xcd = blk & 7;
    const int idx = blk >> 3;                 // 0..255
    const int o   = xcd + ((idx & 15) << 3);
    const int b   = idx >> 4;

    const int tid  = threadIdx.x;
    const int wave = tid >> 6;
    const int lane = tid & 63;
    const int q    = lane >> 3;
    const int s    = lane & 7;
    const int i0   = wave * IPW;

    const float4* pT4  = (const float4*)poseT + ((size_t)(b * CI_ + i0)) * 16 + q * 2;
    const float4* tT4  = (const float4*)TT    + ((size_t)(i0 * CO_ + o)) * 16 + s * 2;
    const float*  actb = act + b * CI_ + i0;

    __shared__ __align__(16) float prbuf[NWAVE][8 * 68];  // 8 rows x (64+4 pad)
    __shared__ __align__(16) float wbuf[NWAVE * 32];
    __shared__ float sA[NWAVE][QS];
    __shared__ float sB[NWAVE][QS];
    __shared__ float sC[NWAVE];

    float* prw = prbuf[wave];

    float V[IPW];
    float Sw = 0.f, SwV = 0.f, SwV2 = 0.f;

    // sweep 1: fill V + act-weighted moments (w_i = act_i; R=1/CO cancels)
#pragma unroll
    for (int j = 0; j < IPW; ++j) {
        float4 a0 = pT4[j * 16];
        float4 a1 = pT4[j * 16 + 1];
        float4 b0 = tT4[(size_t)j * (CO_ * 16)];
        float4 b1 = tT4[(size_t)j * (CO_ * 16) + 1];
        float v;
        v = a0.x * b0.x;
        v = fmaf(a0.y, b0.y, v);
        v = fmaf(a0.z, b0.z, v);
        v = fmaf(a0.w, b0.w, v);
        v = fmaf(a1.x, b1.x, v);
        v = fmaf(a1.y, b1.y, v);
        v = fmaf(a1.z, b1.z, v);
        v = fmaf(a1.w, b1.w, v);
        V[j] = v;
        float ai = actb[j];
        Sw  += ai;
        SwV  = fmaf(ai, v, SwV);
        SwV2 = fmaf(ai * v, v, SwV2);
    }

    auto block_reduce = [&]() {
        __syncthreads();                       // protect previous round's reads
        sA[wave][lane] = SwV;
        sB[wave][lane] = SwV2;
        if (lane == 0) sC[wave] = Sw;
        __syncthreads();
        float a = 0.f, bb = 0.f, c = 0.f;
#pragma unroll
        for (int w = 0; w < NWAVE; ++w) {
            a  += sA[w][lane];
            bb += sB[w][lane];
            c  += sC[w];
        }
        SwV = a; SwV2 = bb; Sw = c;
    };

    block_reduce();
    float invSw = (Sw != 0.f) ? 1.f / Sw : 0.f;
    float mu  = SwV * invSw;
    float var = fmaxf(fmaf(-mu, mu, SwV2 * invSw), 1e-30f);
    float is  = 1.f / sqrtf(var);

    // sweeps 2,3: w_j = a_j * E_j, E_j = sum_qs exp2(-(V-mu)^2 * is^2 / (2 ln2))
    // (act_out, L1 norm, 1/sqrt(2pi), and the uniform is-factor all cancel in r)
#pragma unroll 1
    for (int it = 0; it < 2; ++it) {
        const float cc = is * is * NEG_HALF_LOG2E;
#pragma unroll
        for (int p = 0; p < 4; ++p) {
            // stage pr for 8 j's (per-wave private tile; DS ops in-order per wave)
#pragma unroll
            for (int jj = 0; jj < 8; ++jj) {
                float d = V[p * 8 + jj] - mu;
                prw[jj * 68 + lane] = exp2f(d * cc * d);
            }
            // row-sum: lane handles row r = lane>>3, slice (lane&7)*8..+7
            const int r  = lane >> 3;
            const int co = (lane & 7) * 8;
            const float4* rp = (const float4*)&prw[r * 68 + co];
            float4 x0 = rp[0], x1 = rp[1];
            float ps = ((x0.x + x0.y) + (x0.z + x0.w)) +
                       ((x1.x + x1.y) + (x1.z + x1.w));
            ps = dpp_add<0xB1>(ps);    // xor1
            ps = dpp_add<0x4E>(ps);    // xor2
            ps = dpp_add<0x141>(ps);   // row_half_mirror == xor4 after 1,2
            float wj = actb[p * 8 + r] * ps;     // full E_j on all 8 lanes
            if ((lane & 7) == 0) wbuf[wave * 32 + p * 8 + r] = wj;
        }
        // accumulate from the 32 broadcast w's
        const float4* wb4 = (const float4*)&wbuf[wave * 32];
        Sw = 0.f; SwV = 0.f; SwV2 = 0.f;
#pragma unroll
        for (int k = 0; k < 8; ++k) {
            float4 w4 = wb4[k];
            float v0 = V[4 * k + 0], v1 = V[4 * k + 1];
            float v2 = V[4 * k + 2], v3 = V[4 * k + 3];
            Sw += w4.x; SwV = fmaf(w4.x, v0, SwV); SwV2 = fmaf(w4.x * v0, v0, SwV2);
            Sw += w4.y; SwV = fmaf(w4.y, v1, SwV); SwV2 = fmaf(w4.y * v1, v1, SwV2);
            Sw += w4.z; SwV = fmaf(w4.z, v2, SwV); SwV2 = fmaf(w4.z * v2, v2, SwV2);
            Sw += w4.w; SwV = fmaf(w4.w, v3, SwV); SwV2 = fmaf(w4.w * v3, v3, SwV2);
        }
        block_reduce();
        invSw = (Sw != 0.f) ? 1.f / Sw : 0.f;
        mu  = SwV * invSw;
        var = fmaxf(fmaf(-mu, mu, SwV2 * invSw), 1e-30f);
        is  = 1.f / sqrtf(var);
    }

    if (wave == 0) {
        mu_out[((size_t)b * CO_ + o) * QS + lane] = mu;
        // logits = LAMB*(bias_a - bias_b*1 - sum_qs 0.5*log var) + softmax-inv const
        float sl = wave_sum64_shfl(0.5f * logf(var));
        if (lane == 0)
            logits[b * CO_ + o] = LAMB * (bias_a[o] - bias_b[o] - sl);
    }
}

// ---------- legacy path (R9, proven): used only if ws_size is too small ----------
__global__ __launch_bounds__(256, 4) void capsule_legacy(
    const float* __restrict__ pose,
    const float* __restrict__ trans,
    const float* __restrict__ act,
    const float* __restrict__ bias_a,
    const float* __restrict__ bias_b,
    float* __restrict__ logits,
    float* __restrict__ mu_out)
{
    const int blk  = blockIdx.x;
    const int b    = blk >> 7;
    const int o    = blk & 127;
    const int tid  = threadIdx.x;
    const int wave = tid >> 6;
    const int lane = tid & 63;
    const int q    = lane >> 3;
    const int s    = lane & 7;
    const int i0   = wave * 128;

    const float* poseb = pose + ((size_t)b * CI_ + i0) * QS + lane;
    const float* tb    = trans + ((size_t)i0 * CO_ + o) * QS + lane;
    const float* actb  = act + b * CI_ + i0;

    __shared__ float sSwV[4][QS];
    __shared__ float sSwV2[4][QS];
    __shared__ float sSw[4];

    float Sw = 0.f, SwV = 0.f, SwV2 = 0.f;

    auto do_sweep = [&](bool use_prob, float mu_r, float is_r) {
        Sw = 0.f; SwV = 0.f; SwV2 = 0.f;
        for (int j = 0; j < 128; ++j) {
            float pe = poseb[(size_t)j * QS];
            float te = tb[(size_t)j * (CO_ * QS)];
            float ai = actb[j];
            float V = 0.f;
#pragma unroll
            for (int p = 0; p < 8; ++p) {
                float a = __shfl(pe, p * 8 + q, 64);
                float t = __shfl(te, p * 8 + s, 64);
                V = fmaf(a, t, V);
            }
            float w;
            if (use_prob) {
                float d  = V - mu_r;
                float e  = d * is_r;
                float pr = is_r * exp2f(e * e * NEG_HALF_LOG2E);
                w = ai * wave_sum64_shfl(pr);
            } else {
                w = ai;
            }
            Sw += w;
            SwV  = fmaf(w, V, SwV);
            SwV2 = fmaf(w * V, V, SwV2);
        }
        __syncthreads();
        sSwV[wave][lane]  = SwV;
        sSwV2[wave][lane] = SwV2;
        if (lane == 0) sSw[wave] = Sw;
        __syncthreads();
        float a = 0.f, c = 0.f, d2 = 0.f;
#pragma unroll
        for (int w2 = 0; w2 < 4; ++w2) {
            a  += sSwV[w2][lane];
            d2 += sSwV2[w2][lane];
            c  += sSw[w2];
        }
        SwV = a; SwV2 = d2; Sw = c;
    };

    float mu = 0.f, var = 1.f, is = 1.f;
    do_sweep(false, 0.f, 0.f);
    {
        float invSw = (Sw != 0.f) ? 1.f / Sw : 0.f;
        mu = SwV * invSw; var = fmaxf(fmaf(-mu, mu, SwV2 * invSw), 1e-30f);
        is = 1.f / sqrtf(var);
    }
    do_sweep(true, mu, is);
    {
        float invSw = (Sw != 0.f) ? 1.f / Sw : 0.f;
        mu = SwV * invSw; var = fmaxf(fmaf(-mu, mu, SwV2 * invSw), 1e-30f);
        is = 1.f / sqrtf(var);
    }
    do_sweep(true, mu, is);
    {
        float invSw = (Sw != 0.f) ? 1.f / Sw : 0.f;
        mu = SwV * invSw; var = fmaxf(fmaf(-mu, mu, SwV2 * invSw), 1e-30f);
    }

    if (wave == 0) {
        mu_out[((size_t)b * CO_ + o) * QS + lane] = mu;
        float sl = wave_sum64_shfl(0.5f * logf(var));
        if (lane == 0)
            logits[b * CO_ + o] = LAMB * (bias_a[o] - bias_b[o] - sl);
    }
}

__global__ __launch_bounds__(128) void softmax_kernel(
    const float* __restrict__ logits, float* __restrict__ out)
{
    const int b = blockIdx.x;
    const int t = threadIdx.x;
    float l = logits[b * CO_ + t];

    __shared__ float sm[2];
    __shared__ float s2[2];

    float m = l;
#pragma unroll
    for (int k = 32; k >= 1; k >>= 1) m = fmaxf(m, __shfl_xor(m, k, 64));
    if ((t & 63) == 0) sm[t >> 6] = m;
    __syncthreads();
    m = fmaxf(sm[0], sm[1]);

    float e = expf(l - m);
    float ssum = e;
#pragma unroll
    for (int k = 32; k >= 1; k >>= 1) ssum += __shfl_xor(ssum, k, 64);
    if ((t & 63) == 0) s2[t >> 6] = ssum;
    __syncthreads();
    float tot = s2[0] + s2[1];

    out[b * CO_ + t] = e / tot;
}

extern "C" void kernel_launch(void* const* d_in, const int* in_sizes, int n_in,
                              void* d_out, int out_size, void* d_ws, size_t ws_size,
                              hipStream_t stream) {
    // Size-keyed binding (no-op under documented order; sizes are all distinct).
    const float *act = nullptr, *pose = nullptr, *trans = nullptr;
    const float *bias_a = nullptr, *bias_b = nullptr;
    for (int i = 0; i < n_in; ++i) {
        const float* p = (const float*)d_in[i];
        switch (in_sizes[i]) {
            case 8192:    act = p; break;
            case 524288:  pose = p; break;
            case 4194304: trans = p; break;
            case 128:     if (!bias_a) bias_a = p; else bias_b = p; break;
            default: break;
        }
    }
    if (!act || !pose || !trans || !bias_a || !bias_b) {
        act    = (const float*)d_in[0];
        pose   = (const float*)d_in[1];
        trans  = (const float*)d_in[2];
        bias_a = (const float*)d_in[3];
        bias_b = (const float*)d_in[4];
    }

    float* out_act = (float*)d_out;                // f32 [16,128]
    float* out_mu  = out_act + B_ * CO_;           // f32 [16,128,8,8]

    const size_t NEEDED = (size_t)(524288 + 4194304 + 2048) * 4;   // ~18.9 MB

    if (ws_size >= NEEDED) {
        float* poseT  = (float*)d_ws;              // 524288
        float* TT     = poseT + 524288;            // 4194304
        float* logits = TT + 4194304;              // 2048

        transpose_kernel<<<dim3(4194304 / 256), dim3(256), 0, stream>>>(
            pose, trans, poseT, TT);
        capsule_kernel<<<dim3(B_ * CO_), dim3(1024), 0, stream>>>(
            poseT, TT, act, bias_a, bias_b, logits, out_mu);
        softmax_kernel<<<dim3(B_), dim3(128), 0, stream>>>(logits, out_act);
    } else {
        float* logits = (float*)d_ws;              // 2048 floats
        capsule_legacy<<<dim3(B_ * CO_), dim3(256), 0, stream>>>(
            pose, trans, act, bias_a, bias_b, logits, out_mu);
        softmax_kernel<<<dim3(B_), dim3(128), 0, stream>>>(logits, out_act);
    }
}